// Round 9
// baseline (9890.443 us; speedup 1.0000x reference)
//
#include <hip/hip_runtime.h>
#include <math.h>

#define BDIM 1024
#define BR   64
#define D    128
#define SPD  130      // state LDS row stride (doubles); rows 16B-aligned, b128 reads aligned
#define SWOP 12       // sWo row stride (floats), 16B-aligned rows
#define TT   32
#define NB   8
#define NL   3

__device__ __forceinline__ double c19_act_d(double x) {
    const double PI_D = 3.14159265358979323846;
    const double L6   = 6.0 * PI_D;
    double scaled = x * (1.0 / PI_D);
    double n = floor(scaled);
    double t = scaled - n;
    double h = t * (1.0 - t);
    double halfn = n * 0.5;
    double fr = halfn - floor(halfn);   // 0.0 (even n) or 0.5 (odd n)
    double sgn = (fr < 0.25) ? 1.0 : -1.0;
    double core = PI_D * (sgn * h + 4.0 * h * h);
    double r = core;
    r = (x <= -L6) ? (x + L6) : r;
    r = (x >=  L6) ? (x - L6) : r;
    return r;
}

__global__ __launch_bounds__(BDIM, 4) void miniphi_kernel(
    const float* __restrict__ x,  const float* __restrict__ Wi, const float* __restrict__ bi,
    const float* __restrict__ Wo, const float* __restrict__ bo,
    const float* __restrict__ g_state, const float* __restrict__ b_state,
    const float* __restrict__ Ws, const float* __restrict__ bs,
    const float* __restrict__ gs, const float* __restrict__ betas,
    float* __restrict__ out)
{
    __shared__ double sStateD[BR][SPD];    // 66560 B  recurrent state (rows shared by wave PAIRS)
    __shared__ float  sW[D * D];           // 65536 B  current layer W, row-major [k*128+c]
    __shared__ float  sWi[NB][D];          //  4096 B
    __shared__ float  sWo[D][SWOP];        //  6144 B
    __shared__ float  sBi[D], sGst[D], sBst[D];  // 1536 B
    __shared__ double sGsD[NL][D];         //  3072 B  g (f64, exact)
    __shared__ double sGW[NL][D];          //  3072 B  (g @ W)[c]
    __shared__ double sBWbs[NL][D];        //  3072 B  (beta @ W)[c] + bs[c]
    __shared__ double sRstd[BR];           //   512 B
    __shared__ double sMu2[BR];            //   512 B  mu * rstd
    __shared__ float  sBo[NB];             // total ~150 KB -> 1 block/CU, 16 waves

    const int tid = threadIdx.x;

    for (int i = tid; i < NB * D; i += BDIM) sWi[i >> 7][i & 127] = Wi[i];
    for (int i = tid; i < D * NB; i += BDIM) sWo[i >> 3][i & 7] = Wo[i];
    for (int i = tid; i < D; i += BDIM) { sBi[i] = bi[i]; sGst[i] = g_state[i]; sBst[i] = b_state[i]; }
    for (int i = tid; i < NL * D; i += BDIM) sGsD[i >> 7][i & 127] = (double)gs[i];
    if (tid < NB) sBo[tid] = bo[tid];
    for (int i = tid; i < BR * D; i += BDIM) sStateD[i >> 7][i & 127] = 0.0;
    // LN-fold per-layer column vectors (f64): gW[c] = sum_k g[k]W[k][c]; bWbs[c] = sum_k beta[k]W[k][c] + bs[c]
    if (tid < NL * D) {
        int l = tid >> 7, c = tid & 127;
        const float* wl = Ws + (size_t)l * D * D;
        double gw = 0.0, bw = 0.0;
        for (int k = 0; k < D; ++k) {
            double w = (double)wl[k * D + c];
            gw = fma((double)gs[l * D + k], w, gw);
            bw = fma((double)betas[l * D + k], w, bw);
        }
        sGW[l][c] = gw;
        sBWbs[l][c] = bw + (double)bs[l * D + c];
    }
    __syncthreads();

    const int rLN = tid >> 4;        // 0..63 : LN row (wave w owns rows 4w..4w+3)
    const int sLN = tid & 15;        // 0..15 : lane owns cols {sLN + 16*j}
    const int rg  = tid >> 7;        // 0..7  : GEMM row group (8 rows, shared by wave pair)
    const int cc  = tid & 127;       // GEMM col
    const int r0  = rg * 8;
    const size_t rowg = (size_t)blockIdx.x * BR;

    float4 wreg[4];                  // T14 W prefetch registers

    for (int t = 0; t < TT; ++t) {
        // prefetch layer-0 W (L2-resident; hides under step 1)
        #pragma unroll
        for (int it = 0; it < 4; ++it)
            wreg[it] = *(const float4*)&Ws[it * (BDIM * 4) + tid * 4];

        // ---------- step 1: state = 0.618*(LN(h)*g+b) + 0.382*(x_t @ Wi + bi) (own-wave rows) ----------
        {
            const float* xp = x + (rowg + (size_t)rLN) * (TT * NB) + (size_t)t * NB;
            float4 xa = *(const float4*)(xp);
            float4 xb = *(const float4*)(xp + 4);
            double xv[8] = {(double)xa.x, (double)xa.y, (double)xa.z, (double)xa.w,
                            (double)xb.x, (double)xb.y, (double)xb.z, (double)xb.w};

            double v[8];
            #pragma unroll
            for (int j = 0; j < 8; ++j) v[j] = sStateD[rLN][sLN + 16 * j];

            double sum = 0.0;
            #pragma unroll
            for (int j = 0; j < 8; ++j) sum += v[j];
            sum += __shfl_xor(sum, 1); sum += __shfl_xor(sum, 2);
            sum += __shfl_xor(sum, 4); sum += __shfl_xor(sum, 8);
            double mu = sum * (1.0 / 128.0);
            double sq = 0.0;
            #pragma unroll
            for (int j = 0; j < 8; ++j) { double dd = v[j] - mu; sq += dd * dd; }
            sq += __shfl_xor(sq, 1); sq += __shfl_xor(sq, 2);
            sq += __shfl_xor(sq, 4); sq += __shfl_xor(sq, 8);
            double rstd = 1.0 / sqrt(sq * (1.0 / 128.0) + 1e-5);

            #pragma unroll
            for (int j = 0; j < 8; ++j) {
                int c = sLN + 16 * j;
                double inp = (double)sBi[c];
                #pragma unroll
                for (int k = 0; k < 8; ++k)
                    inp = fma(xv[k], (double)sWi[k][c], inp);
                double ln = (v[j] - mu) * rstd * (double)sGst[c] + (double)sBst[c];
                sStateD[rLN][c] = 0.618 * ln + 0.382 * inp;
            }
        }

        // ---------- step 2: 3 residual layers; GEMM reads state directly (LN folded) ----------
        for (int layer = 0; layer < NL; ++layer) {
            // LN reductions only (own-wave rows) -> sMu2, sRstd
            {
                double v[8];
                #pragma unroll
                for (int j = 0; j < 8; ++j) v[j] = sStateD[rLN][sLN + 16 * j];
                double sum = 0.0;
                #pragma unroll
                for (int j = 0; j < 8; ++j) sum += v[j];
                sum += __shfl_xor(sum, 1); sum += __shfl_xor(sum, 2);
                sum += __shfl_xor(sum, 4); sum += __shfl_xor(sum, 8);
                double mu = sum * (1.0 / 128.0);
                double sq = 0.0;
                #pragma unroll
                for (int j = 0; j < 8; ++j) { double dd = v[j] - mu; sq += dd * dd; }
                sq += __shfl_xor(sq, 1); sq += __shfl_xor(sq, 2);
                sq += __shfl_xor(sq, 4); sq += __shfl_xor(sq, 8);
                double rstd = 1.0 / sqrt(sq * (1.0 / 128.0) + 1e-5);
                if (sLN == 0) { sRstd[rLN] = rstd; sMu2[rLN] = mu * rstd; }
            }
            // stage W (row-major, coalesced b128 writes) from prefetched regs
            #pragma unroll
            for (int it = 0; it < 4; ++it)
                *(float4*)&sW[it * (BDIM * 4) + tid * 4] = wreg[it];
            __syncthreads();   // BAR1: sW ready; state/sMu2/sRstd stable for GEMM

            // prefetch next layer's W (hides under GEMM)
            if (layer + 1 < NL) {
                const float* wsrc = Ws + (size_t)(layer + 1) * D * D;
                #pragma unroll
                for (int it = 0; it < 4; ++it)
                    wreg[it] = *(const float4*)&wsrc[it * (BDIM * 4) + tid * 4];
            }

            // GEMM: 8 rows x 1 col per thread; dot'_rc = sum_k state[r][k]*g[k]*W[k][c]
            double acc[8];
            #pragma unroll
            for (int r = 0; r < 8; ++r) acc[r] = 0.0;

            const double* gvec = sGsD[layer];
            #pragma unroll 4
            for (int k0 = 0; k0 < D; k0 += 4) {
                double b0 = gvec[k0 + 0] * (double)sW[(k0 + 0) * D + cc];
                double b1 = gvec[k0 + 1] * (double)sW[(k0 + 1) * D + cc];
                double b2 = gvec[k0 + 2] * (double)sW[(k0 + 2) * D + cc];
                double b3 = gvec[k0 + 3] * (double)sW[(k0 + 3) * D + cc];
                #pragma unroll
                for (int r = 0; r < 8; ++r) {
                    double2 a01 = *(const double2*)&sStateD[r0 + r][k0];
                    double2 a23 = *(const double2*)&sStateD[r0 + r][k0 + 2];
                    double ta = acc[r];
                    ta = fma(a01.x, b0, ta);
                    ta = fma(a01.y, b1, ta);
                    ta = fma(a23.x, b2, ta);
                    ta = fma(a23.y, b3, ta);
                    acc[r] = ta;
                }
            }

            // epilogue part 1 (no state writes): y = rstd*dot - (mu*rstd)*gW + (bW+bs); add = c19(y)
            double add[8];
            {
                double gwc = sGW[layer][cc];
                double bwc = sBWbs[layer][cc];
                #pragma unroll
                for (int r = 0; r < 8; ++r) {
                    double rstd_r = sRstd[r0 + r];
                    double m2_r   = sMu2[r0 + r];
                    double y = fma(rstd_r, acc[r], fma(-m2_r, gwc, bwc));
                    add[r] = c19_act_d(y);
                }
            }
            __syncthreads();   // BAR2a: all GEMM reads of state complete -> writes allowed

            // epilogue part 2: state[r][cc] += add[r]  (element owned exclusively by this thread)
            #pragma unroll
            for (int r = 0; r < 8; ++r)
                sStateD[r0 + r][cc] += add[r];
            __syncthreads();   // BAR2b: state updated -> next phase may read
        }

        // ---------- step 3: out = state @ Wo + bo (own-wave rows) ----------
        {
            double accj[8];
            #pragma unroll
            for (int j = 0; j < 8; ++j) accj[j] = 0.0;
            #pragma unroll
            for (int u = 0; u < 8; ++u) {
                int k = sLN + 16 * u;
                double s = sStateD[rLN][k];
                float4 w0 = *(const float4*)&sWo[k][0];
                float4 w1 = *(const float4*)&sWo[k][4];
                accj[0] = fma(s, (double)w0.x, accj[0]);
                accj[1] = fma(s, (double)w0.y, accj[1]);
                accj[2] = fma(s, (double)w0.z, accj[2]);
                accj[3] = fma(s, (double)w0.w, accj[3]);
                accj[4] = fma(s, (double)w1.x, accj[4]);
                accj[5] = fma(s, (double)w1.y, accj[5]);
                accj[6] = fma(s, (double)w1.z, accj[6]);
                accj[7] = fma(s, (double)w1.w, accj[7]);
            }
            #pragma unroll
            for (int j = 0; j < 8; ++j) {
                accj[j] += __shfl_xor(accj[j], 1);
                accj[j] += __shfl_xor(accj[j], 2);
                accj[j] += __shfl_xor(accj[j], 4);
                accj[j] += __shfl_xor(accj[j], 8);
            }
            if (sLN < NB)
                out[((rowg + (size_t)rLN) * TT + (size_t)t) * NB + sLN] =
                    (float)(accj[sLN] + (double)sBo[sLN]);
        }
    }
}

extern "C" void kernel_launch(void* const* d_in, const int* in_sizes, int n_in,
                              void* d_out, int out_size, void* d_ws, size_t ws_size,
                              hipStream_t stream) {
    const float* x       = (const float*)d_in[0];
    const float* Wi      = (const float*)d_in[1];
    const float* bi      = (const float*)d_in[2];
    const float* Wo      = (const float*)d_in[3];
    const float* bo      = (const float*)d_in[4];
    const float* g_state = (const float*)d_in[5];
    const float* b_state = (const float*)d_in[6];
    const float* Ws      = (const float*)d_in[7];
    const float* bs      = (const float*)d_in[8];
    const float* gs      = (const float*)d_in[9];
    const float* betas   = (const float*)d_in[10];
    float* out = (float*)d_out;

    const int B = in_sizes[0] / (TT * NB);   // 65536
    dim3 grid(B / BR), block(BDIM);
    hipLaunchKernelGGL(miniphi_kernel, grid, block, 0, stream,
                       x, Wi, bi, Wo, bo, g_state, b_state, Ws, bs, gs, betas, out);
}

// Round 10
// 9419.344 us; speedup vs baseline: 1.0500x; 1.0500x over previous
//
#include <hip/hip_runtime.h>
#include <math.h>

#define BDIM 1024
#define BR   64
#define D    128
#define SPD  130      // state LDS row stride (doubles); rows 16B-aligned
#define SWOP 12       // sWo row stride (floats)
#define TT   32
#define NB   8
#define NL   3

__device__ __forceinline__ double c19_act_d(double x) {
    const double PI_D = 3.14159265358979323846;
    const double L6   = 6.0 * PI_D;
    double scaled = x * (1.0 / PI_D);
    double n = floor(scaled);
    double t = scaled - n;
    double h = t * (1.0 - t);
    double halfn = n * 0.5;
    double fr = halfn - floor(halfn);   // 0.0 (even n) or 0.5 (odd n)
    double sgn = (fr < 0.25) ? 1.0 : -1.0;
    double core = PI_D * (sgn * h + 4.0 * h * h);
    double r = core;
    r = (x <= -L6) ? (x + L6) : r;
    r = (x >=  L6) ? (x - L6) : r;
    return r;
}

// Stage 64 KB W tile into LDS via async global->LDS (no VGPR round-trip).
// LDS dest = wave-uniform base + lane*16B (linear row-major, matches layout).
__device__ __forceinline__ void stage_W_async(const float* __restrict__ wsrc,
                                              float* sW, int tid) {
    const int wv   = tid >> 6;    // wave 0..15
    const int lane = tid & 63;
    #pragma unroll
    for (int it = 0; it < 4; ++it) {
        int base = it * 4096 + wv * 256;            // floats; 64 lanes x 4 floats = 256
        const float* g = wsrc + base + lane * 4;
        float* l = sW + base;                        // wave-uniform LDS base
        __builtin_amdgcn_global_load_lds(
            (const __attribute__((address_space(1))) void*)g,
            (__attribute__((address_space(3))) void*)l,
            16, 0, 0);
    }
}

__global__ __launch_bounds__(BDIM, 1) void miniphi_kernel(
    const float* __restrict__ x,  const float* __restrict__ Wi, const float* __restrict__ bi,
    const float* __restrict__ Wo, const float* __restrict__ bo,
    const float* __restrict__ g_state, const float* __restrict__ b_state,
    const float* __restrict__ Ws, const float* __restrict__ bs,
    const float* __restrict__ gs, const float* __restrict__ betas,
    float* __restrict__ out)
{
    __shared__ double sStateD[BR][SPD];    // 66560 B  recurrent state
    __shared__ float  sW[D * D];           // 65536 B  current layer W, row-major [k*128+c]
    __shared__ float  sWi[NB][D];
    __shared__ float  sWo[D][SWOP];
    __shared__ float  sBi[D], sGst[D], sBst[D];
    __shared__ double sGsD[NL][D];         // g (f64, exact)
    __shared__ double sGW[NL][D];          // (g @ W)[c]
    __shared__ double sBWbs[NL][D];        // (beta @ W)[c] + bs[c]
    __shared__ double sRstd[BR];
    __shared__ double sMu2[BR];            // mu * rstd
    __shared__ float  sBo[NB];             // total ~150 KB -> 1 block/CU, 16 waves

    const int tid = threadIdx.x;

    for (int i = tid; i < NB * D; i += BDIM) sWi[i >> 7][i & 127] = Wi[i];
    for (int i = tid; i < D * NB; i += BDIM) sWo[i >> 3][i & 7] = Wo[i];
    for (int i = tid; i < D; i += BDIM) { sBi[i] = bi[i]; sGst[i] = g_state[i]; sBst[i] = b_state[i]; }
    for (int i = tid; i < NL * D; i += BDIM) sGsD[i >> 7][i & 127] = (double)gs[i];
    if (tid < NB) sBo[tid] = bo[tid];
    for (int i = tid; i < BR * D; i += BDIM) sStateD[i >> 7][i & 127] = 0.0;
    // LN-fold per-layer column vectors (f64)
    if (tid < NL * D) {
        int l = tid >> 7, c = tid & 127;
        const float* wl = Ws + (size_t)l * D * D;
        double gw = 0.0, bw = 0.0;
        for (int k = 0; k < D; ++k) {
            double w = (double)wl[k * D + c];
            gw = fma((double)gs[l * D + k], w, gw);
            bw = fma((double)betas[l * D + k], w, bw);
        }
        sGW[l][c] = gw;
        sBWbs[l][c] = bw + (double)bs[l * D + c];
    }
    __syncthreads();

    const int rLN = tid >> 4;        // 0..63 : LN row (wave w owns rows 4w..4w+3)
    const int sLN = tid & 15;        // 0..15 : lane owns cols {sLN + 16*j}
    const int rg  = tid >> 7;        // 0..7  : GEMM row group (8 rows, wave pair)
    const int cc  = tid & 127;       // GEMM col
    const int r0  = rg * 8;
    const size_t rowg = (size_t)blockIdx.x * BR;

    for (int t = 0; t < TT; ++t) {
        // async-stage layer-0 W (sW readers all finished before prior BAR2a)
        stage_W_async(Ws, sW, tid);

        // ---------- step 1: state = 0.618*(LN(h)*g+b) + 0.382*(x_t @ Wi + bi) (own-wave rows) ----------
        {
            const float* xp = x + (rowg + (size_t)rLN) * (TT * NB) + (size_t)t * NB;
            float4 xa = *(const float4*)(xp);
            float4 xb = *(const float4*)(xp + 4);
            double xv[8] = {(double)xa.x, (double)xa.y, (double)xa.z, (double)xa.w,
                            (double)xb.x, (double)xb.y, (double)xb.z, (double)xb.w};

            double v[8];
            #pragma unroll
            for (int j = 0; j < 8; ++j) v[j] = sStateD[rLN][sLN + 16 * j];

            double sum = 0.0;
            #pragma unroll
            for (int j = 0; j < 8; ++j) sum += v[j];
            sum += __shfl_xor(sum, 1); sum += __shfl_xor(sum, 2);
            sum += __shfl_xor(sum, 4); sum += __shfl_xor(sum, 8);
            double mu = sum * (1.0 / 128.0);
            double sq = 0.0;
            #pragma unroll
            for (int j = 0; j < 8; ++j) { double dd = v[j] - mu; sq += dd * dd; }
            sq += __shfl_xor(sq, 1); sq += __shfl_xor(sq, 2);
            sq += __shfl_xor(sq, 4); sq += __shfl_xor(sq, 8);
            double rstd = 1.0 / sqrt(sq * (1.0 / 128.0) + 1e-5);

            #pragma unroll
            for (int j = 0; j < 8; ++j) {
                int c = sLN + 16 * j;
                double inp = (double)sBi[c];
                #pragma unroll
                for (int k = 0; k < 8; ++k)
                    inp = fma(xv[k], (double)sWi[k][c], inp);
                double ln = (v[j] - mu) * rstd * (double)sGst[c] + (double)sBst[c];
                sStateD[rLN][c] = 0.618 * ln + 0.382 * inp;
            }
        }

        // ---------- step 2: 3 residual layers; GEMM reads state directly (LN folded) ----------
        for (int layer = 0; layer < NL; ++layer) {
            // LN reductions only (own-wave rows) -> sMu2, sRstd
            {
                double v[8];
                #pragma unroll
                for (int j = 0; j < 8; ++j) v[j] = sStateD[rLN][sLN + 16 * j];
                double sum = 0.0;
                #pragma unroll
                for (int j = 0; j < 8; ++j) sum += v[j];
                sum += __shfl_xor(sum, 1); sum += __shfl_xor(sum, 2);
                sum += __shfl_xor(sum, 4); sum += __shfl_xor(sum, 8);
                double mu = sum * (1.0 / 128.0);
                double sq = 0.0;
                #pragma unroll
                for (int j = 0; j < 8; ++j) { double dd = v[j] - mu; sq += dd * dd; }
                sq += __shfl_xor(sq, 1); sq += __shfl_xor(sq, 2);
                sq += __shfl_xor(sq, 4); sq += __shfl_xor(sq, 8);
                double rstd = 1.0 / sqrt(sq * (1.0 / 128.0) + 1e-5);
                if (sLN == 0) { sRstd[rLN] = rstd; sMu2[rLN] = mu * rstd; }
            }
            __syncthreads();   // BAR1: sW staged (vmcnt drained) + sMu2/sRstd visible

            // GEMM: 8 rows x 1 col per thread; dot'_rc = sum_k state[r][k]*g[k]*W[k][c]
            double acc[8];
            #pragma unroll
            for (int r = 0; r < 8; ++r) acc[r] = 0.0;

            const double* gvec = sGsD[layer];
            #pragma unroll 4
            for (int k0 = 0; k0 < D; k0 += 4) {
                double b0 = gvec[k0 + 0] * (double)sW[(k0 + 0) * D + cc];
                double b1 = gvec[k0 + 1] * (double)sW[(k0 + 1) * D + cc];
                double b2 = gvec[k0 + 2] * (double)sW[(k0 + 2) * D + cc];
                double b3 = gvec[k0 + 3] * (double)sW[(k0 + 3) * D + cc];
                #pragma unroll
                for (int r = 0; r < 8; ++r) {
                    double2 a01 = *(const double2*)&sStateD[r0 + r][k0];
                    double2 a23 = *(const double2*)&sStateD[r0 + r][k0 + 2];
                    double ta = acc[r];
                    ta = fma(a01.x, b0, ta);
                    ta = fma(a01.y, b1, ta);
                    ta = fma(a23.x, b2, ta);
                    ta = fma(a23.y, b3, ta);
                    acc[r] = ta;
                }
            }

            // epilogue part 1: y = rstd*dot - (mu*rstd)*gW + (bW+bs); add = c19(y)
            double add[8];
            {
                double gwc = sGW[layer][cc];
                double bwc = sBWbs[layer][cc];
                #pragma unroll
                for (int r = 0; r < 8; ++r) {
                    double rstd_r = sRstd[r0 + r];
                    double m2_r   = sMu2[r0 + r];
                    double y = fma(rstd_r, acc[r], fma(-m2_r, gwc, bwc));
                    add[r] = c19_act_d(y);
                }
            }
            __syncthreads();   // BAR2a: all GEMM reads (state + sW) complete

            // async-stage next layer's W now that sW readers are done
            if (layer + 1 < NL)
                stage_W_async(Ws + (size_t)(layer + 1) * D * D, sW, tid);

            // epilogue part 2: state[r][cc] += add[r] (exclusive element ownership)
            #pragma unroll
            for (int r = 0; r < 8; ++r)
                sStateD[r0 + r][cc] += add[r];
            __syncthreads();   // BAR2b: state updated -> next phase may read
        }

        // ---------- step 3: out = state @ Wo + bo (own-wave rows) ----------
        {
            double accj[8];
            #pragma unroll
            for (int j = 0; j < 8; ++j) accj[j] = 0.0;
            #pragma unroll
            for (int u = 0; u < 8; ++u) {
                int k = sLN + 16 * u;
                double s = sStateD[rLN][k];
                float4 w0 = *(const float4*)&sWo[k][0];
                float4 w1 = *(const float4*)&sWo[k][4];
                accj[0] = fma(s, (double)w0.x, accj[0]);
                accj[1] = fma(s, (double)w0.y, accj[1]);
                accj[2] = fma(s, (double)w0.z, accj[2]);
                accj[3] = fma(s, (double)w0.w, accj[3]);
                accj[4] = fma(s, (double)w1.x, accj[4]);
                accj[5] = fma(s, (double)w1.y, accj[5]);
                accj[6] = fma(s, (double)w1.z, accj[6]);
                accj[7] = fma(s, (double)w1.w, accj[7]);
            }
            #pragma unroll
            for (int j = 0; j < 8; ++j) {
                accj[j] += __shfl_xor(accj[j], 1);
                accj[j] += __shfl_xor(accj[j], 2);
                accj[j] += __shfl_xor(accj[j], 4);
                accj[j] += __shfl_xor(accj[j], 8);
            }
            if (sLN < NB)
                out[((rowg + (size_t)rLN) * TT + (size_t)t) * NB + sLN] =
                    (float)(accj[sLN] + (double)sBo[sLN]);
        }
    }
}

extern "C" void kernel_launch(void* const* d_in, const int* in_sizes, int n_in,
                              void* d_out, int out_size, void* d_ws, size_t ws_size,
                              hipStream_t stream) {
    const float* x       = (const float*)d_in[0];
    const float* Wi      = (const float*)d_in[1];
    const float* bi      = (const float*)d_in[2];
    const float* Wo      = (const float*)d_in[3];
    const float* bo      = (const float*)d_in[4];
    const float* g_state = (const float*)d_in[5];
    const float* b_state = (const float*)d_in[6];
    const float* Ws      = (const float*)d_in[7];
    const float* bs      = (const float*)d_in[8];
    const float* gs      = (const float*)d_in[9];
    const float* betas   = (const float*)d_in[10];
    float* out = (float*)d_out;

    const int B = in_sizes[0] / (TT * NB);   // 65536
    dim3 grid(B / BR), block(BDIM);
    hipLaunchKernelGGL(miniphi_kernel, grid, block, 0, stream,
                       x, Wi, bi, Wo, bo, g_state, b_state, Ws, bs, gs, betas, out);
}

// Round 11
// 9413.276 us; speedup vs baseline: 1.0507x; 1.0006x over previous
//
#include <hip/hip_runtime.h>
#include <math.h>

#define BDIM 1024
#define BR   64
#define D    128
#define SPD  130      // state LDS row stride (doubles); rows 16B-aligned
#define SWOP 12       // sWo row stride (floats)
#define TT   32
#define NB   8
#define NL   3

__device__ __forceinline__ double c19_act_d(double x) {
    const double PI_D = 3.14159265358979323846;
    const double L6   = 6.0 * PI_D;
    double scaled = x * (1.0 / PI_D);
    double n = floor(scaled);
    double t = scaled - n;
    double h = t * (1.0 - t);
    double halfn = n * 0.5;
    double fr = halfn - floor(halfn);   // 0.0 (even n) or 0.5 (odd n)
    double sgn = (fr < 0.25) ? 1.0 : -1.0;
    double core = PI_D * (sgn * h + 4.0 * h * h);
    double r = core;
    r = (x <= -L6) ? (x + L6) : r;
    r = (x >=  L6) ? (x - L6) : r;
    return r;
}

// Stage 64 KB W tile into LDS via async global->LDS (no VGPR round-trip).
__device__ __forceinline__ void stage_W_async(const float* __restrict__ wsrc,
                                              float* sW, int tid) {
    const int wv   = tid >> 6;    // wave 0..15
    const int lane = tid & 63;
    #pragma unroll
    for (int it = 0; it < 4; ++it) {
        int base = it * 4096 + wv * 256;            // floats; 64 lanes x 4 floats = 256
        const float* g = wsrc + base + lane * 4;
        float* l = sW + base;                        // wave-uniform LDS base
        __builtin_amdgcn_global_load_lds(
            (const __attribute__((address_space(1))) void*)g,
            (__attribute__((address_space(3))) void*)l,
            16, 0, 0);
    }
}

// Exactly 4 waves/EU (1 block/CU is LDS-forced anyway) -> 128 VGPR budget, no spill.
__global__ __attribute__((amdgpu_flat_work_group_size(1024, 1024), amdgpu_waves_per_eu(4, 4)))
void miniphi_kernel(
    const float* __restrict__ x,  const float* __restrict__ Wi, const float* __restrict__ bi,
    const float* __restrict__ Wo, const float* __restrict__ bo,
    const float* __restrict__ g_state, const float* __restrict__ b_state,
    const float* __restrict__ Ws, const float* __restrict__ bs,
    const float* __restrict__ gs, const float* __restrict__ betas,
    float* __restrict__ out)
{
    __shared__ double sStateD[BR][SPD];    // 66560 B  recurrent state
    __shared__ float  sW[D * D];           // 65536 B  current layer W, row-major [k*128+c]
    __shared__ float  sWi[NB][D];
    __shared__ float  sWo[D][SWOP];
    __shared__ float  sBi[D], sGst[D], sBst[D];
    __shared__ double sGsD[NL][D];         // g (f64, exact)
    __shared__ double sGW[NL][D];          // (g @ W)[c]
    __shared__ double sBWbs[NL][D];        // (beta @ W)[c] + bs[c]
    __shared__ double sRstd[BR];
    __shared__ double sMu2[BR];            // mu * rstd
    __shared__ float  sBo[NB];             // total ~150 KB -> 1 block/CU, 16 waves

    const int tid = threadIdx.x;

    for (int i = tid; i < NB * D; i += BDIM) sWi[i >> 7][i & 127] = Wi[i];
    for (int i = tid; i < D * NB; i += BDIM) sWo[i >> 3][i & 7] = Wo[i];
    for (int i = tid; i < D; i += BDIM) { sBi[i] = bi[i]; sGst[i] = g_state[i]; sBst[i] = b_state[i]; }
    for (int i = tid; i < NL * D; i += BDIM) sGsD[i >> 7][i & 127] = (double)gs[i];
    if (tid < NB) sBo[tid] = bo[tid];
    for (int i = tid; i < BR * D; i += BDIM) sStateD[i >> 7][i & 127] = 0.0;
    // LN-fold per-layer column vectors (f64)
    if (tid < NL * D) {
        int l = tid >> 7, c = tid & 127;
        const float* wl = Ws + (size_t)l * D * D;
        double gw = 0.0, bw = 0.0;
        for (int k = 0; k < D; ++k) {
            double w = (double)wl[k * D + c];
            gw = fma((double)gs[l * D + k], w, gw);
            bw = fma((double)betas[l * D + k], w, bw);
        }
        sGW[l][c] = gw;
        sBWbs[l][c] = bw + (double)bs[l * D + c];
    }
    __syncthreads();

    const int rLN = tid >> 4;        // 0..63 : LN row (wave w owns rows 4w..4w+3)
    const int sLN = tid & 15;        // 0..15 : lane owns cols {sLN + 16*j}
    const int rg  = tid >> 7;        // 0..7  : GEMM row group (8 rows, wave pair)
    const int cc  = tid & 127;       // GEMM col
    const int r0  = rg * 8;
    const size_t rowg = (size_t)blockIdx.x * BR;

    for (int t = 0; t < TT; ++t) {
        // async-stage layer-0 W (sW readers all finished before prior BAR2a)
        stage_W_async(Ws, sW, tid);

        // ---------- step 1: state = 0.618*(LN(h)*g+b) + 0.382*(x_t @ Wi + bi) (own-wave rows) ----------
        {
            const float* xp = x + (rowg + (size_t)rLN) * (TT * NB) + (size_t)t * NB;
            float4 xa = *(const float4*)(xp);
            float4 xb = *(const float4*)(xp + 4);
            double xv[8] = {(double)xa.x, (double)xa.y, (double)xa.z, (double)xa.w,
                            (double)xb.x, (double)xb.y, (double)xb.z, (double)xb.w};

            double v[8];
            #pragma unroll
            for (int j = 0; j < 8; ++j) v[j] = sStateD[rLN][sLN + 16 * j];

            double sum = 0.0;
            #pragma unroll
            for (int j = 0; j < 8; ++j) sum += v[j];
            sum += __shfl_xor(sum, 1); sum += __shfl_xor(sum, 2);
            sum += __shfl_xor(sum, 4); sum += __shfl_xor(sum, 8);
            double mu = sum * (1.0 / 128.0);
            double sq = 0.0;
            #pragma unroll
            for (int j = 0; j < 8; ++j) { double dd = v[j] - mu; sq += dd * dd; }
            sq += __shfl_xor(sq, 1); sq += __shfl_xor(sq, 2);
            sq += __shfl_xor(sq, 4); sq += __shfl_xor(sq, 8);
            double rstd = 1.0 / sqrt(sq * (1.0 / 128.0) + 1e-5);

            #pragma unroll
            for (int j = 0; j < 8; ++j) {
                int c = sLN + 16 * j;
                double inp = (double)sBi[c];
                #pragma unroll
                for (int k = 0; k < 8; ++k)
                    inp = fma(xv[k], (double)sWi[k][c], inp);
                double ln = (v[j] - mu) * rstd * (double)sGst[c] + (double)sBst[c];
                sStateD[rLN][c] = 0.618 * ln + 0.382 * inp;
            }
        }

        // ---------- step 2: 3 residual layers; GEMM reads state directly (LN folded) ----------
        for (int layer = 0; layer < NL; ++layer) {
            // LN reductions only (own-wave rows) -> sMu2, sRstd
            {
                double v[8];
                #pragma unroll
                for (int j = 0; j < 8; ++j) v[j] = sStateD[rLN][sLN + 16 * j];
                double sum = 0.0;
                #pragma unroll
                for (int j = 0; j < 8; ++j) sum += v[j];
                sum += __shfl_xor(sum, 1); sum += __shfl_xor(sum, 2);
                sum += __shfl_xor(sum, 4); sum += __shfl_xor(sum, 8);
                double mu = sum * (1.0 / 128.0);
                double sq = 0.0;
                #pragma unroll
                for (int j = 0; j < 8; ++j) { double dd = v[j] - mu; sq += dd * dd; }
                sq += __shfl_xor(sq, 1); sq += __shfl_xor(sq, 2);
                sq += __shfl_xor(sq, 4); sq += __shfl_xor(sq, 8);
                double rstd = 1.0 / sqrt(sq * (1.0 / 128.0) + 1e-5);
                if (sLN == 0) { sRstd[rLN] = rstd; sMu2[rLN] = mu * rstd; }
            }
            __syncthreads();   // BAR1: sW staged (vmcnt drained) + sMu2/sRstd visible

            // GEMM: 8 rows x 1 col per thread; dot'_rc = sum_k state[r][k]*g[k]*W[k][c]
            double acc[8];
            #pragma unroll
            for (int r = 0; r < 8; ++r) acc[r] = 0.0;

            const double* gvec = sGsD[layer];
            #pragma unroll 4
            for (int k0 = 0; k0 < D; k0 += 4) {
                double b0 = gvec[k0 + 0] * (double)sW[(k0 + 0) * D + cc];
                double b1 = gvec[k0 + 1] * (double)sW[(k0 + 1) * D + cc];
                double b2 = gvec[k0 + 2] * (double)sW[(k0 + 2) * D + cc];
                double b3 = gvec[k0 + 3] * (double)sW[(k0 + 3) * D + cc];
                #pragma unroll
                for (int r = 0; r < 8; ++r) {
                    double2 a01 = *(const double2*)&sStateD[r0 + r][k0];
                    double2 a23 = *(const double2*)&sStateD[r0 + r][k0 + 2];
                    double ta = acc[r];
                    ta = fma(a01.x, b0, ta);
                    ta = fma(a01.y, b1, ta);
                    ta = fma(a23.x, b2, ta);
                    ta = fma(a23.y, b3, ta);
                    acc[r] = ta;
                }
            }

            // epilogue part 1: y = rstd*dot - (mu*rstd)*gW + (bW+bs); add = c19(y)
            double add[8];
            {
                double gwc = sGW[layer][cc];
                double bwc = sBWbs[layer][cc];
                #pragma unroll
                for (int r = 0; r < 8; ++r) {
                    double rstd_r = sRstd[r0 + r];
                    double m2_r   = sMu2[r0 + r];
                    double y = fma(rstd_r, acc[r], fma(-m2_r, gwc, bwc));
                    add[r] = c19_act_d(y);
                }
            }
            __syncthreads();   // BAR2a: all GEMM reads (state + sW) complete

            // async-stage next layer's W now that sW readers are done
            if (layer + 1 < NL)
                stage_W_async(Ws + (size_t)(layer + 1) * D * D, sW, tid);

            // epilogue part 2: state[r][cc] += add[r] (exclusive element ownership)
            #pragma unroll
            for (int r = 0; r < 8; ++r)
                sStateD[r0 + r][cc] += add[r];
            __syncthreads();   // BAR2b: state updated -> next phase may read
        }

        // ---------- step 3: out = state @ Wo + bo (own-wave rows) ----------
        {
            double accj[8];
            #pragma unroll
            for (int j = 0; j < 8; ++j) accj[j] = 0.0;
            #pragma unroll
            for (int u = 0; u < 8; ++u) {
                int k = sLN + 16 * u;
                double s = sStateD[rLN][k];
                float4 w0 = *(const float4*)&sWo[k][0];
                float4 w1 = *(const float4*)&sWo[k][4];
                accj[0] = fma(s, (double)w0.x, accj[0]);
                accj[1] = fma(s, (double)w0.y, accj[1]);
                accj[2] = fma(s, (double)w0.z, accj[2]);
                accj[3] = fma(s, (double)w0.w, accj[3]);
                accj[4] = fma(s, (double)w1.x, accj[4]);
                accj[5] = fma(s, (double)w1.y, accj[5]);
                accj[6] = fma(s, (double)w1.z, accj[6]);
                accj[7] = fma(s, (double)w1.w, accj[7]);
            }
            #pragma unroll
            for (int j = 0; j < 8; ++j) {
                accj[j] += __shfl_xor(accj[j], 1);
                accj[j] += __shfl_xor(accj[j], 2);
                accj[j] += __shfl_xor(accj[j], 4);
                accj[j] += __shfl_xor(accj[j], 8);
            }
            if (sLN < NB)
                out[((rowg + (size_t)rLN) * TT + (size_t)t) * NB + sLN] =
                    (float)(accj[sLN] + (double)sBo[sLN]);
        }
    }
}

extern "C" void kernel_launch(void* const* d_in, const int* in_sizes, int n_in,
                              void* d_out, int out_size, void* d_ws, size_t ws_size,
                              hipStream_t stream) {
    const float* x       = (const float*)d_in[0];
    const float* Wi      = (const float*)d_in[1];
    const float* bi      = (const float*)d_in[2];
    const float* Wo      = (const float*)d_in[3];
    const float* bo      = (const float*)d_in[4];
    const float* g_state = (const float*)d_in[5];
    const float* b_state = (const float*)d_in[6];
    const float* Ws      = (const float*)d_in[7];
    const float* bs      = (const float*)d_in[8];
    const float* gs      = (const float*)d_in[9];
    const float* betas   = (const float*)d_in[10];
    float* out = (float*)d_out;

    const int B = in_sizes[0] / (TT * NB);   // 65536
    dim3 grid(B / BR), block(BDIM);
    hipLaunchKernelGGL(miniphi_kernel, grid, block, 0, stream,
                       x, Wi, bi, Wo, bo, g_state, b_state, Ws, bs, gs, betas, out);
}